// Round 7
// baseline (1025.864 us; speedup 1.0000x reference)
//
#include <hip/hip_runtime.h>
#include <math.h>

#define N_NODES  100000
#define N_EDGES  800000
#define F        64
#define N_GRAPHS 64
#define GPAD     68          // f32 LDS tile row stride (padding -> conflict-free A-frag reads)
#define ECAP     1024        // staged edges per chunk (block max ~590 for this data; loop handles any)

typedef _Float16 half8 __attribute__((ext_vector_type(8)));
typedef float    f32x4 __attribute__((ext_vector_type(4)));

// ---------------- workspace layout (bytes) ----------------
#define OFF_BUFA 0u           // ushort[N*F] 12,800,000 (xs / hs ping; rank aliases head)
#define OFF_BUFB 12800000u    // ushort[N*F] 12,800,000
#define OFF_DIS  25600000u    // float[N]       400,000
#define OFF_DEG  26000000u    // int[N]         400,000
#define OFF_ROWP 26400000u    // int[N+1]       400,004 (pad to 64)
#define OFF_COL  26800064u    // int[E]       3,200,000
#define OFF_BSUM 30000064u    // int[128]
#define OFF_WT   30000576u    // _Float16[3*4096] 24,576
// total ~30.0 MB

__device__ inline ushort f2bf(float f) {               // round-to-nearest-even
    uint u = __float_as_uint(f);
    u = (u + 0x7FFFu + ((u >> 16) & 1u)) >> 16;
    return (ushort)u;
}
__device__ inline float bf2f(ushort s) {
    return __uint_as_float(((uint)s) << 16);
}

__global__ void k_zero(int* __restrict__ p, int n) {
    int i = blockIdx.x * blockDim.x + threadIdx.x;
    if (i < n) p[i] = 0;
}

// degree count AND per-edge rank (return value of the atomic we already pay)
__global__ void k_degree(const int* __restrict__ dst, int* __restrict__ degcnt,
                         int* __restrict__ rank) {
    int e = blockIdx.x * blockDim.x + threadIdx.x;
    if (e < N_EDGES) rank[e] = atomicAdd(&degcnt[dst[e]], 1);
}

// block scan of degcnt -> rowptr[i+1]; block totals -> bsum; dis fused.
__global__ void k_scan1(const int* __restrict__ degcnt, int* __restrict__ rowptr,
                        int* __restrict__ bsum, float* __restrict__ dis) {
    __shared__ int s[1024];
    int i = blockIdx.x * 1024 + threadIdx.x;
    int v = (i < N_NODES) ? degcnt[i] : 0;
    if (i < N_NODES) dis[i] = rsqrtf((float)v + 1.0f);
    s[threadIdx.x] = v;
    __syncthreads();
    for (int off = 1; off < 1024; off <<= 1) {
        int t = (threadIdx.x >= off) ? s[threadIdx.x - off] : 0;
        __syncthreads();
        s[threadIdx.x] += t;
        __syncthreads();
    }
    if (i < N_NODES) rowptr[i + 1] = s[threadIdx.x];
    if (threadIdx.x == 1023) bsum[blockIdx.x] = s[1023];
}

// parallel exclusive scan of the 98 block sums
__global__ void k_scan2(int* __restrict__ bsum, int nb) {
    __shared__ int s[128];
    int t = threadIdx.x;
    int v = (t < nb) ? bsum[t] : 0;
    s[t] = v;
    __syncthreads();
    for (int off = 1; off < 128; off <<= 1) {
        int u = (t >= off) ? s[t - off] : 0;
        __syncthreads();
        s[t] += u;
        __syncthreads();
    }
    if (t < nb) bsum[t] = s[t] - v;   // exclusive
}

__global__ void k_scan3(int* __restrict__ rowptr, const int* __restrict__ bsum) {
    int i = blockIdx.x * 1024 + threadIdx.x;
    if (i < N_NODES) rowptr[i + 1] += bsum[blockIdx.x];
    if (i == 0) rowptr[0] = 0;
}

// no atomics: position comes from rowptr + precomputed rank
__global__ void k_fill(const int* __restrict__ src, const int* __restrict__ dst,
                       const int* __restrict__ rowptr, const int* __restrict__ rank,
                       int* __restrict__ col) {
    int e = blockIdx.x * blockDim.x + threadIdx.x;
    if (e < N_EDGES) {
        int d = dst[e];
        col[rowptr[d] + rank[e]] = src[e];
    }
}

// xs = bf16(dis * x)  (layer-1 gather source; 8 elems/thread)
__global__ void k_prepx(const float* __restrict__ x, const float* __restrict__ dis,
                        ushort* __restrict__ xs) {
    int t = blockIdx.x * blockDim.x + threadIdx.x;
    if (t < N_NODES * 8) {
        int n = t >> 3;
        float d = dis[n];
        const float4* px = (const float4*)(x + (size_t)t * 8);
        float4 a = px[0], b = px[1];
        ushort o[8] = { f2bf(d*a.x), f2bf(d*a.y), f2bf(d*a.z), f2bf(d*a.w),
                        f2bf(d*b.x), f2bf(d*b.y), f2bf(d*b.z), f2bf(d*b.w) };
        *(uint4*)(xs + (size_t)t * 8) = *(const uint4*)o;
    }
}

// Wt[w][f][k] = f16(W_w[k][f])  — transposed f16 weights for MFMA B-fragments
__global__ void k_prepw(const float* __restrict__ W1, const float* __restrict__ W2,
                        const float* __restrict__ W3, _Float16* __restrict__ Wt) {
    int t = blockIdx.x * blockDim.x + threadIdx.x;
    if (t < 3 * 4096) {
        int wsel = t >> 12, i = t & 4095;
        int k = i >> 6, f = i & 63;
        const float* Ws = (wsel == 0) ? W1 : (wsel == 1) ? W2 : W3;
        Wt[wsel * 4096 + f * 64 + k] = (_Float16)Ws[k * 64 + f];
    }
}

// Fused GCN layer, edge-parallel aggregation:
//   g[n] (f32 LDS) = hs[n] + sum_{e:dst=n} hs[src]   (hs pre-scaled by dis; ds_add_f32)
//   h'   = relu( (dis[n]*g[n])·W + b );  out = bf16( SCALE ? dis*h' : h' )
// Block = 64 nodes, 4 waves. Block's CSR edge range is contiguous: staged to LDS
// (coalesced) + tagged with local dst row; waves split the flat edge list evenly.
// Per edge: uniform LDS read -> 128B row gather -> ds_add into g. 8-deep unroll,
// no cross-iteration deps. dis row-scale folds into f32->f16 A-frag conversion.
template<bool RELU, bool SCALE>
__global__ __launch_bounds__(256) void k_layer(const ushort* __restrict__ hs,
                                               const int* __restrict__ rowptr,
                                               const int* __restrict__ col,
                                               const float* __restrict__ dis,
                                               const _Float16* __restrict__ Wt,
                                               const float* __restrict__ bias,
                                               ushort* __restrict__ hout) {
    __shared__ float g[64 * GPAD];
    __shared__ uint  epack[ECAP];
    __shared__ int   rp[65];
    int lane = threadIdx.x & 63;
    int w    = __builtin_amdgcn_readfirstlane(threadIdx.x >> 6);
    int chunk = blockIdx.x * 64;

    if (threadIdx.x < 65) {
        int n = chunk + threadIdx.x;
        rp[threadIdx.x] = rowptr[n <= N_NODES ? n : N_NODES];
    }
    // self-loop init: g[row] = hs[chunk+row] (own strip, coalesced 128B reads)
#pragma unroll 4
    for (int r = 0; r < 16; ++r) {
        int row = w * 16 + r;
        int n = chunk + row;
        g[row * GPAD + lane] = (n < N_NODES) ? bf2f(hs[(size_t)n * F + lane]) : 0.f;
    }
    __syncthreads();

    int E0 = rp[0], E1 = rp[64];
    for (int EC = E0; EC < E1; EC += ECAP) {
        int ecnt = min(E1 - EC, ECAP);
        // stage col coalesced
        for (int j = threadIdx.x; j < ecnt; j += 256)
            epack[j] = (uint)col[EC + j];
        __syncthreads();
        // tag staged edges with local dst row (node ranges are disjoint -> race-free)
        if (threadIdx.x < 64) {
            int i = threadIdx.x;
            int a = rp[i], b = rp[i + 1];
            if (a < EC) a = EC;
            int bb = EC + ecnt; if (b > bb) b = bb;
            uint tag = (uint)i << 20;
            for (int e = a; e < b; ++e) epack[e - EC] |= tag;
        }
        __syncthreads();
        // even flat split of edges across the 4 waves
        int s = __builtin_amdgcn_readfirstlane((w * ecnt) >> 2);
        int t = __builtin_amdgcn_readfirstlane(((w + 1) * ecnt) >> 2);
        int e = s;
        for (; e + 7 < t; e += 8) {
            uint p0 = __builtin_amdgcn_readfirstlane(epack[e]);
            uint p1 = __builtin_amdgcn_readfirstlane(epack[e + 1]);
            uint p2 = __builtin_amdgcn_readfirstlane(epack[e + 2]);
            uint p3 = __builtin_amdgcn_readfirstlane(epack[e + 3]);
            uint p4 = __builtin_amdgcn_readfirstlane(epack[e + 4]);
            uint p5 = __builtin_amdgcn_readfirstlane(epack[e + 5]);
            uint p6 = __builtin_amdgcn_readfirstlane(epack[e + 6]);
            uint p7 = __builtin_amdgcn_readfirstlane(epack[e + 7]);
            float v0 = bf2f(hs[(size_t)(p0 & 0xFFFFF) * F + lane]);
            float v1 = bf2f(hs[(size_t)(p1 & 0xFFFFF) * F + lane]);
            float v2 = bf2f(hs[(size_t)(p2 & 0xFFFFF) * F + lane]);
            float v3 = bf2f(hs[(size_t)(p3 & 0xFFFFF) * F + lane]);
            float v4 = bf2f(hs[(size_t)(p4 & 0xFFFFF) * F + lane]);
            float v5 = bf2f(hs[(size_t)(p5 & 0xFFFFF) * F + lane]);
            float v6 = bf2f(hs[(size_t)(p6 & 0xFFFFF) * F + lane]);
            float v7 = bf2f(hs[(size_t)(p7 & 0xFFFFF) * F + lane]);
            atomicAdd(&g[(p0 >> 20) * GPAD + lane], v0);
            atomicAdd(&g[(p1 >> 20) * GPAD + lane], v1);
            atomicAdd(&g[(p2 >> 20) * GPAD + lane], v2);
            atomicAdd(&g[(p3 >> 20) * GPAD + lane], v3);
            atomicAdd(&g[(p4 >> 20) * GPAD + lane], v4);
            atomicAdd(&g[(p5 >> 20) * GPAD + lane], v5);
            atomicAdd(&g[(p6 >> 20) * GPAD + lane], v6);
            atomicAdd(&g[(p7 >> 20) * GPAD + lane], v7);
        }
        for (; e < t; ++e) {
            uint p = __builtin_amdgcn_readfirstlane(epack[e]);
            float v = bf2f(hs[(size_t)(p & 0xFFFFF) * F + lane]);
            atomicAdd(&g[(p >> 20) * GPAD + lane], v);
        }
        __syncthreads();   // edges done before epack reuse / MFMA reads
    }

    // ---------- MFMA: C[16x64] = (dis * g_strip) · W ----------
    int l15 = lane & 15, lh = lane >> 4;
    half8 bfrag[2][4];
#pragma unroll
    for (int ks = 0; ks < 2; ++ks)
#pragma unroll
        for (int nt = 0; nt < 4; ++nt)
            bfrag[ks][nt] = *(const half8*)(Wt + (nt * 16 + l15) * 64 + ks * 32 + lh * 8);

    int arow = w * 16 + l15;
    int an = chunk + arow;
    float dr = dis[an < N_NODES ? an : (N_NODES - 1)];

    f32x4 acc[4] = {};
#pragma unroll
    for (int ks = 0; ks < 2; ++ks) {
        const float* gp = &g[arow * GPAD + ks * 32 + lh * 8];
        half8 a;
#pragma unroll
        for (int j = 0; j < 8; ++j) a[j] = (_Float16)(dr * gp[j]);
#pragma unroll
        for (int nt = 0; nt < 4; ++nt)
            acc[nt] = __builtin_amdgcn_mfma_f32_16x16x32_f16(a, bfrag[ks][nt], acc[nt], 0, 0, 0);
    }
    __syncthreads();   // all waves done reading g (f32) before ushort-epilogue overwrite

    // ---------- epilogue -> LDS (bf16, stride 64) -> coalesced global ----------
    float bvals[4];
#pragma unroll
    for (int nt = 0; nt < 4; ++nt) bvals[nt] = bias[nt * 16 + l15];
    ushort* gd = (ushort*)g;
#pragma unroll
    for (int r = 0; r < 4; ++r) {
        int row = w * 16 + lh * 4 + r;
        int ng = chunk + row;
        float ds2 = 1.f;
        if (SCALE) ds2 = dis[ng < N_NODES ? ng : (N_NODES - 1)];
#pragma unroll
        for (int nt = 0; nt < 4; ++nt) {
            float v = acc[nt][r] + bvals[nt];
            if (RELU) v = fmaxf(v, 0.f);
            if (SCALE) v *= ds2;
            gd[row * 64 + nt * 16 + l15] = f2bf(v);
        }
    }
    __syncthreads();
    int nvalid = N_NODES - chunk; if (nvalid > 64) nvalid = 64;
    for (int c = threadIdx.x; c < 64 * 8; c += 256) {   // 16B chunks: 8 per row
        int row = c >> 3;
        if (row < nvalid) {
            uint4 v = *(const uint4*)(gd + row * 64 + (c & 7) * 8);
            *(uint4*)(hout + (size_t)(chunk + row) * F + (c & 7) * 8) = v;
        }
    }
}

__global__ void k_pool_init(float* __restrict__ out) {
    int i = blockIdx.x * blockDim.x + threadIdx.x;
    if (i < N_GRAPHS * F) out[i] = -INFINITY;
}

__device__ inline void atomicMaxFloat(float* addr, float v) {
    if (v >= 0.f) atomicMax((int*)addr, __float_as_int(v));
    else          atomicMin((unsigned int*)addr, __float_as_uint(v));
}

// batch is sorted: each wave scans a contiguous chunk, flushes on boundary.
__global__ __launch_bounds__(256) void k_pool(const ushort* __restrict__ h,
                                              const int* __restrict__ batch,
                                              float* __restrict__ out) {
    int lane = threadIdx.x & 63;
    int wid  = __builtin_amdgcn_readfirstlane((blockIdx.x * blockDim.x + threadIdx.x) >> 6);
    int nwaves = (gridDim.x * blockDim.x) >> 6;
    int per = (N_NODES + nwaves - 1) / nwaves;
    int n0 = wid * per, n1 = min(N_NODES, n0 + per);
    if (n0 >= n1) return;
    float acc = -INFINITY;
    int cur = batch[n0];
    for (int n = n0; n < n1; ++n) {
        int g = batch[n];
        if (g != cur) {
            atomicMaxFloat(&out[cur * F + lane], acc);
            acc = -INFINITY; cur = g;
        }
        acc = fmaxf(acc, bf2f(h[(size_t)n * F + lane]));
    }
    atomicMaxFloat(&out[cur * F + lane], acc);
}

extern "C" void kernel_launch(void* const* d_in, const int* in_sizes, int n_in,
                              void* d_out, int out_size, void* d_ws, size_t ws_size,
                              hipStream_t stream) {
    const float* x     = (const float*)d_in[0];
    const int*   ei    = (const int*)d_in[1];
    const int*   batch = (const int*)d_in[2];
    const float* W1 = (const float*)d_in[3];
    const float* b1 = (const float*)d_in[4];
    const float* W2 = (const float*)d_in[5];
    const float* b2 = (const float*)d_in[6];
    const float* W3 = (const float*)d_in[7];
    const float* b3 = (const float*)d_in[8];
    const int* src = ei;
    const int* dst = ei + N_EDGES;

    char* ws = (char*)d_ws;
    ushort*   bufA   = (ushort*)(ws + OFF_BUFA);
    int*      rank   = (int*)(ws + OFF_BUFA);     // alias: live only during CSR build
    ushort*   bufB   = (ushort*)(ws + OFF_BUFB);
    float*    dis    = (float*)(ws + OFF_DIS);
    int*      degcnt = (int*)(ws + OFF_DEG);
    int*      rowptr = (int*)(ws + OFF_ROWP);
    int*      col    = (int*)(ws + OFF_COL);
    int*      bsum   = (int*)(ws + OFF_BSUM);
    _Float16* wt     = (_Float16*)(ws + OFF_WT);
    float*    out    = (float*)d_out;

    // CSR build
    k_zero<<<(N_NODES + 255) / 256, 256, 0, stream>>>(degcnt, N_NODES);
    k_degree<<<(N_EDGES + 255) / 256, 256, 0, stream>>>(dst, degcnt, rank);
    k_scan1<<<98, 1024, 0, stream>>>(degcnt, rowptr, bsum, dis);
    k_scan2<<<1, 128, 0, stream>>>(bsum, 98);
    k_scan3<<<98, 1024, 0, stream>>>(rowptr, bsum);
    k_fill<<<(N_EDGES + 255) / 256, 256, 0, stream>>>(src, dst, rowptr, rank, col);

    // prep: xs = bf16(dis*x) (overwrites rank region), Wt = f16 transposed weights
    k_prepx<<<(N_NODES * 8 + 255) / 256, 256, 0, stream>>>(x, dis, bufA);
    k_prepw<<<48, 256, 0, stream>>>(W1, W2, W3, wt);

    const int LBLOCKS = (N_NODES + 63) / 64;   // 1563
    k_layer<true,  true ><<<LBLOCKS, 256, 0, stream>>>(bufA, rowptr, col, dis, wt,        b1, bufB);
    k_layer<true,  true ><<<LBLOCKS, 256, 0, stream>>>(bufB, rowptr, col, dis, wt + 4096, b2, bufA);
    k_layer<false, false><<<LBLOCKS, 256, 0, stream>>>(bufA, rowptr, col, dis, wt + 8192, b3, bufB);

    // global max pool
    k_pool_init<<<(N_GRAPHS * F + 255) / 256, 256, 0, stream>>>(out);
    k_pool<<<512, 256, 0, stream>>>(bufB, batch, out);
}

// Round 8
// 258.342 us; speedup vs baseline: 3.9710x; 3.9710x over previous
//
#include <hip/hip_runtime.h>
#include <math.h>

#define N_NODES  100000
#define N_EDGES  800000
#define F        64
#define N_GRAPHS 64
#define GPAD     68          // f32 LDS tile row stride: 68%32=4 -> A-frag b128 reads 2-way (free)

typedef _Float16 half8 __attribute__((ext_vector_type(8)));
typedef float    f32x4 __attribute__((ext_vector_type(4)));

// ---------------- workspace layout (bytes) ----------------
#define OFF_BUFA 0u           // ushort[N*F] 12,800,000 (xs / hs ping; rank aliases head)
#define OFF_BUFB 12800000u    // ushort[N*F] 12,800,000
#define OFF_DIS  25600000u    // float[N]       400,000
#define OFF_DEG  26000000u    // int[N]         400,000
#define OFF_ROWP 26400000u    // int[N+1]       400,004 (pad to 64)
#define OFF_COL  26800064u    // int[E]       3,200,000
#define OFF_BSUM 30000064u    // int[128]
#define OFF_WT   30000576u    // _Float16[3*4096] 24,576
// total ~30.0 MB

__device__ inline ushort f2bf(float f) {               // round-to-nearest-even
    uint u = __float_as_uint(f);
    u = (u + 0x7FFFu + ((u >> 16) & 1u)) >> 16;
    return (ushort)u;
}
__device__ inline float bf2f(ushort s) {
    return __uint_as_float(((uint)s) << 16);
}

__global__ void k_zero(int* __restrict__ p, int n) {
    int i = blockIdx.x * blockDim.x + threadIdx.x;
    if (i < n) p[i] = 0;
}

// degree count AND per-edge rank (return value of the atomic we already pay)
__global__ void k_degree(const int* __restrict__ dst, int* __restrict__ degcnt,
                         int* __restrict__ rank) {
    int e = blockIdx.x * blockDim.x + threadIdx.x;
    if (e < N_EDGES) rank[e] = atomicAdd(&degcnt[dst[e]], 1);
}

// block scan of degcnt -> rowptr[i+1]; block totals -> bsum; dis fused.
__global__ void k_scan1(const int* __restrict__ degcnt, int* __restrict__ rowptr,
                        int* __restrict__ bsum, float* __restrict__ dis) {
    __shared__ int s[1024];
    int i = blockIdx.x * 1024 + threadIdx.x;
    int v = (i < N_NODES) ? degcnt[i] : 0;
    if (i < N_NODES) dis[i] = rsqrtf((float)v + 1.0f);
    s[threadIdx.x] = v;
    __syncthreads();
    for (int off = 1; off < 1024; off <<= 1) {
        int t = (threadIdx.x >= off) ? s[threadIdx.x - off] : 0;
        __syncthreads();
        s[threadIdx.x] += t;
        __syncthreads();
    }
    if (i < N_NODES) rowptr[i + 1] = s[threadIdx.x];
    if (threadIdx.x == 1023) bsum[blockIdx.x] = s[1023];
}

// parallel exclusive scan of the 98 block sums
__global__ void k_scan2(int* __restrict__ bsum, int nb) {
    __shared__ int s[128];
    int t = threadIdx.x;
    int v = (t < nb) ? bsum[t] : 0;
    s[t] = v;
    __syncthreads();
    for (int off = 1; off < 128; off <<= 1) {
        int u = (t >= off) ? s[t - off] : 0;
        __syncthreads();
        s[t] += u;
        __syncthreads();
    }
    if (t < nb) bsum[t] = s[t] - v;   // exclusive
}

__global__ void k_scan3(int* __restrict__ rowptr, const int* __restrict__ bsum) {
    int i = blockIdx.x * 1024 + threadIdx.x;
    if (i < N_NODES) rowptr[i + 1] += bsum[blockIdx.x];
    if (i == 0) rowptr[0] = 0;
}

// no atomics: position comes from rowptr + precomputed rank
__global__ void k_fill(const int* __restrict__ src, const int* __restrict__ dst,
                       const int* __restrict__ rowptr, const int* __restrict__ rank,
                       int* __restrict__ col) {
    int e = blockIdx.x * blockDim.x + threadIdx.x;
    if (e < N_EDGES) {
        int d = dst[e];
        col[rowptr[d] + rank[e]] = src[e];
    }
}

// xs = bf16(dis * x)  (layer-1 gather source; 8 elems/thread)
__global__ void k_prepx(const float* __restrict__ x, const float* __restrict__ dis,
                        ushort* __restrict__ xs) {
    int t = blockIdx.x * blockDim.x + threadIdx.x;
    if (t < N_NODES * 8) {
        int n = t >> 3;
        float d = dis[n];
        const float4* px = (const float4*)(x + (size_t)t * 8);
        float4 a = px[0], b = px[1];
        ushort o[8] = { f2bf(d*a.x), f2bf(d*a.y), f2bf(d*a.z), f2bf(d*a.w),
                        f2bf(d*b.x), f2bf(d*b.y), f2bf(d*b.z), f2bf(d*b.w) };
        *(uint4*)(xs + (size_t)t * 8) = *(const uint4*)o;
    }
}

// Wt[w][f][k] = f16(W_w[k][f])  — transposed f16 weights for MFMA B-fragments
__global__ void k_prepw(const float* __restrict__ W1, const float* __restrict__ W2,
                        const float* __restrict__ W3, _Float16* __restrict__ Wt) {
    int t = blockIdx.x * blockDim.x + threadIdx.x;
    if (t < 3 * 4096) {
        int wsel = t >> 12, i = t & 4095;
        int k = i >> 6, f = i & 63;
        const float* Ws = (wsel == 0) ? W1 : (wsel == 1) ? W2 : W3;
        Wt[wsel * 4096 + f * 64 + k] = (_Float16)Ws[k * 64 + f];
    }
}

// Fused GCN layer (agg-first):
//   g[n] (f32 LDS) = hs[n] + sum_{e:dst=n} hs[src]   (hs pre-scaled by dis)
//   h'   = relu( (dis[n]*g[n])·W + b );  out = bf16( SCALE ? dis*h' : h' )
// Block = 64 nodes, 4 waves; wave owns rows [16w,16w+16) and walks its flat
// contiguous CSR range in chunks of 16: col indices via scalar-pipe s_loads
// (uniform addresses), 16 gathers in flight, register run-accumulate with
// row boundaries tracked scalar-side via v_readlane from a staged boundary
// VGPR; finished rows flushed with fire-and-forget ds_add_f32.
template<bool RELU, bool SCALE>
__global__ __launch_bounds__(256) void k_layer(const ushort* __restrict__ hs,
                                               const int* __restrict__ rowptr,
                                               const int* __restrict__ col,
                                               const float* __restrict__ dis,
                                               const _Float16* __restrict__ Wt,
                                               const float* __restrict__ bias,
                                               ushort* __restrict__ hout) {
    __shared__ float g[64 * GPAD];
    int lane = threadIdx.x & 63;
    int w    = __builtin_amdgcn_readfirstlane(threadIdx.x >> 6);
    int chunk = blockIdx.x * 64;
    int wr16 = w * 16;
    int nb0 = chunk + wr16;

    // self-loop init: g[row] = hs[node] (own strip, coalesced 128B reads)
#pragma unroll
    for (int r = 0; r < 16; ++r) {
        int n = nb0 + r;
        g[(wr16 + r) * GPAD + lane] = (n < N_NODES) ? bf2f(hs[(size_t)n * F + lane]) : 0.f;
    }

    // stage the wave's 16 row-end boundaries into one VGPR (lanes 0..15)
    int bidx = nb0 + 1 + (lane & 15);
    int vb = rowptr[bidx <= N_NODES ? bidx : N_NODES];
    int w0i = nb0 <= N_NODES ? nb0 : N_NODES;
    int we0 = __builtin_amdgcn_readfirstlane(rowptr[w0i]);
    int we1 = __builtin_amdgcn_readlane(vb, 15);

    int r = 0;
    int nextB = __builtin_amdgcn_readlane(vb, 0);
    float acc = 0.f;
    int e = we0;
    int elast = we1 - 1;
    while (e < we1) {
        int cnt = we1 - e; if (cnt > 16) cnt = 16;
        float v[16];
#pragma unroll
        for (int i = 0; i < 16; ++i) {
            int ee = e + i; if (ee > elast) ee = elast;   // clamp: dup loads harmless
            int s = col[ee];                               // uniform -> s_load clause
            v[i] = bf2f(hs[(size_t)s * F + lane]);         // 16 gathers in flight
        }
#pragma unroll
        for (int i = 0; i < 16; ++i) {
            if (i < cnt) {                                 // uniform guard
                while (e + i >= nextB) {                   // scalar row-advance
                    atomicAdd(&g[(wr16 + r) * GPAD + lane], acc);  // ds_add_f32
                    acc = 0.f; ++r;
                    nextB = __builtin_amdgcn_readlane(vb, r);
                }
                acc += v[i];
            }
        }
        e += cnt;
    }
    atomicAdd(&g[(wr16 + r) * GPAD + lane], acc);          // final flush
    __syncthreads();

    // ---------- MFMA: C[16x64] = (dis * g_strip) · W ----------
    int l15 = lane & 15, lh = lane >> 4;
    half8 bfrag[2][4];
#pragma unroll
    for (int ks = 0; ks < 2; ++ks)
#pragma unroll
        for (int nt = 0; nt < 4; ++nt)
            bfrag[ks][nt] = *(const half8*)(Wt + (nt * 16 + l15) * 64 + ks * 32 + lh * 8);

    int arow = wr16 + l15;
    int an = chunk + arow;
    float dr = dis[an < N_NODES ? an : (N_NODES - 1)];

    f32x4 acc4[4] = {};
#pragma unroll
    for (int ks = 0; ks < 2; ++ks) {
        const float* gp = &g[arow * GPAD + ks * 32 + lh * 8];
        half8 a;
#pragma unroll
        for (int j = 0; j < 8; ++j) a[j] = (_Float16)(dr * gp[j]);
#pragma unroll
        for (int nt = 0; nt < 4; ++nt)
            acc4[nt] = __builtin_amdgcn_mfma_f32_16x16x32_f16(a, bfrag[ks][nt], acc4[nt], 0, 0, 0);
    }
    __syncthreads();   // all waves done reading g (f32) before ushort-epilogue overwrite

    // ---------- epilogue -> LDS (bf16, stride 64) -> coalesced global ----------
    float bvals[4];
#pragma unroll
    for (int nt = 0; nt < 4; ++nt) bvals[nt] = bias[nt * 16 + l15];
    ushort* gd = (ushort*)g;
#pragma unroll
    for (int rr = 0; rr < 4; ++rr) {
        int row = wr16 + lh * 4 + rr;
        int ng = chunk + row;
        float ds2 = 1.f;
        if (SCALE) ds2 = dis[ng < N_NODES ? ng : (N_NODES - 1)];
#pragma unroll
        for (int nt = 0; nt < 4; ++nt) {
            float vv = acc4[nt][rr] + bvals[nt];
            if (RELU) vv = fmaxf(vv, 0.f);
            if (SCALE) vv *= ds2;
            gd[row * 64 + nt * 16 + l15] = f2bf(vv);
        }
    }
    __syncthreads();
    int nvalid = N_NODES - chunk; if (nvalid > 64) nvalid = 64;
    for (int c = threadIdx.x; c < 64 * 8; c += 256) {   // 16B chunks: 8 per row
        int row = c >> 3;
        if (row < nvalid) {
            uint4 vv = *(const uint4*)(gd + row * 64 + (c & 7) * 8);
            *(uint4*)(hout + (size_t)(chunk + row) * F + (c & 7) * 8) = vv;
        }
    }
}

__global__ void k_pool_init(float* __restrict__ out) {
    int i = blockIdx.x * blockDim.x + threadIdx.x;
    if (i < N_GRAPHS * F) out[i] = -INFINITY;
}

__device__ inline void atomicMaxFloat(float* addr, float v) {
    if (v >= 0.f) atomicMax((int*)addr, __float_as_int(v));
    else          atomicMin((unsigned int*)addr, __float_as_uint(v));
}

// batch is sorted: each wave scans a contiguous chunk, flushes on boundary.
__global__ __launch_bounds__(256) void k_pool(const ushort* __restrict__ h,
                                              const int* __restrict__ batch,
                                              float* __restrict__ out) {
    int lane = threadIdx.x & 63;
    int wid  = __builtin_amdgcn_readfirstlane((blockIdx.x * blockDim.x + threadIdx.x) >> 6);
    int nwaves = (gridDim.x * blockDim.x) >> 6;
    int per = (N_NODES + nwaves - 1) / nwaves;
    int n0 = wid * per, n1 = min(N_NODES, n0 + per);
    if (n0 >= n1) return;
    float acc = -INFINITY;
    int cur = batch[n0];
    for (int n = n0; n < n1; ++n) {
        int g = batch[n];
        if (g != cur) {
            atomicMaxFloat(&out[cur * F + lane], acc);
            acc = -INFINITY; cur = g;
        }
        acc = fmaxf(acc, bf2f(h[(size_t)n * F + lane]));
    }
    atomicMaxFloat(&out[cur * F + lane], acc);
}

extern "C" void kernel_launch(void* const* d_in, const int* in_sizes, int n_in,
                              void* d_out, int out_size, void* d_ws, size_t ws_size,
                              hipStream_t stream) {
    const float* x     = (const float*)d_in[0];
    const int*   ei    = (const int*)d_in[1];
    const int*   batch = (const int*)d_in[2];
    const float* W1 = (const float*)d_in[3];
    const float* b1 = (const float*)d_in[4];
    const float* W2 = (const float*)d_in[5];
    const float* b2 = (const float*)d_in[6];
    const float* W3 = (const float*)d_in[7];
    const float* b3 = (const float*)d_in[8];
    const int* src = ei;
    const int* dst = ei + N_EDGES;

    char* ws = (char*)d_ws;
    ushort*   bufA   = (ushort*)(ws + OFF_BUFA);
    int*      rank   = (int*)(ws + OFF_BUFA);     // alias: live only during CSR build
    ushort*   bufB   = (ushort*)(ws + OFF_BUFB);
    float*    dis    = (float*)(ws + OFF_DIS);
    int*      degcnt = (int*)(ws + OFF_DEG);
    int*      rowptr = (int*)(ws + OFF_ROWP);
    int*      col    = (int*)(ws + OFF_COL);
    int*      bsum   = (int*)(ws + OFF_BSUM);
    _Float16* wt     = (_Float16*)(ws + OFF_WT);
    float*    out    = (float*)d_out;

    // CSR build
    k_zero<<<(N_NODES + 255) / 256, 256, 0, stream>>>(degcnt, N_NODES);
    k_degree<<<(N_EDGES + 255) / 256, 256, 0, stream>>>(dst, degcnt, rank);
    k_scan1<<<98, 1024, 0, stream>>>(degcnt, rowptr, bsum, dis);
    k_scan2<<<1, 128, 0, stream>>>(bsum, 98);
    k_scan3<<<98, 1024, 0, stream>>>(rowptr, bsum);
    k_fill<<<(N_EDGES + 255) / 256, 256, 0, stream>>>(src, dst, rowptr, rank, col);

    // prep: xs = bf16(dis*x) (overwrites rank region), Wt = f16 transposed weights
    k_prepx<<<(N_NODES * 8 + 255) / 256, 256, 0, stream>>>(x, dis, bufA);
    k_prepw<<<48, 256, 0, stream>>>(W1, W2, W3, wt);

    const int LBLOCKS = (N_NODES + 63) / 64;   // 1563
    k_layer<true,  true ><<<LBLOCKS, 256, 0, stream>>>(bufA, rowptr, col, dis, wt,        b1, bufB);
    k_layer<true,  true ><<<LBLOCKS, 256, 0, stream>>>(bufB, rowptr, col, dis, wt + 4096, b2, bufA);
    k_layer<false, false><<<LBLOCKS, 256, 0, stream>>>(bufA, rowptr, col, dis, wt + 8192, b3, bufB);

    // global max pool
    k_pool_init<<<(N_GRAPHS * F + 255) / 256, 256, 0, stream>>>(out);
    k_pool<<<512, 256, 0, stream>>>(bufB, batch, out);
}

// Round 9
// 203.747 us; speedup vs baseline: 5.0350x; 1.2680x over previous
//
#include <hip/hip_runtime.h>
#include <math.h>

#define N_NODES  100000
#define N_EDGES  800000
#define F        64
#define N_GRAPHS 64

typedef _Float16 half8 __attribute__((ext_vector_type(8)));
typedef float    f32x4 __attribute__((ext_vector_type(4)));

// ---------------- workspace layout (bytes) ----------------
#define OFF_BUFA 0u           // ushort[N*F] 12,800,000 (xs / hs ping; rank aliases head)
#define OFF_BUFB 12800000u    // ushort[N*F] 12,800,000
#define OFF_DIS  25600000u    // float[N]       400,000
#define OFF_DEG  26000000u    // int[N]         400,000
#define OFF_ROWP 26400000u    // int[N+1]       400,004 (pad to 64)
#define OFF_COL  26800064u    // int[E]       3,200,000
#define OFF_BSUM 30000064u    // int[128]
#define OFF_WT   30000576u    // _Float16[3*4096] 24,576
// total ~30.0 MB

__device__ inline ushort f2bf(float f) {               // round-to-nearest-even
    uint u = __float_as_uint(f);
    u = (u + 0x7FFFu + ((u >> 16) & 1u)) >> 16;
    return (ushort)u;
}
__device__ inline float bf2f(ushort s) {
    return __uint_as_float(((uint)s) << 16);
}

__global__ void k_zero(int* __restrict__ p, int n) {
    int i = blockIdx.x * blockDim.x + threadIdx.x;
    if (i < n) p[i] = 0;
}

// degree count AND per-edge rank (return value of the atomic we already pay)
__global__ void k_degree(const int* __restrict__ dst, int* __restrict__ degcnt,
                         int* __restrict__ rank) {
    int e = blockIdx.x * blockDim.x + threadIdx.x;
    if (e < N_EDGES) rank[e] = atomicAdd(&degcnt[dst[e]], 1);
}

// block scan of degcnt -> rowptr[i+1]; block totals -> bsum; dis fused.
__global__ void k_scan1(const int* __restrict__ degcnt, int* __restrict__ rowptr,
                        int* __restrict__ bsum, float* __restrict__ dis) {
    __shared__ int s[1024];
    int i = blockIdx.x * 1024 + threadIdx.x;
    int v = (i < N_NODES) ? degcnt[i] : 0;
    if (i < N_NODES) dis[i] = rsqrtf((float)v + 1.0f);
    s[threadIdx.x] = v;
    __syncthreads();
    for (int off = 1; off < 1024; off <<= 1) {
        int t = (threadIdx.x >= off) ? s[threadIdx.x - off] : 0;
        __syncthreads();
        s[threadIdx.x] += t;
        __syncthreads();
    }
    if (i < N_NODES) rowptr[i + 1] = s[threadIdx.x];
    if (threadIdx.x == 1023) bsum[blockIdx.x] = s[1023];
}

// parallel exclusive scan of the 98 block sums
__global__ void k_scan2(int* __restrict__ bsum, int nb) {
    __shared__ int s[128];
    int t = threadIdx.x;
    int v = (t < nb) ? bsum[t] : 0;
    s[t] = v;
    __syncthreads();
    for (int off = 1; off < 128; off <<= 1) {
        int u = (t >= off) ? s[t - off] : 0;
        __syncthreads();
        s[t] += u;
        __syncthreads();
    }
    if (t < nb) bsum[t] = s[t] - v;   // exclusive
}

__global__ void k_scan3(int* __restrict__ rowptr, const int* __restrict__ bsum) {
    int i = blockIdx.x * 1024 + threadIdx.x;
    if (i < N_NODES) rowptr[i + 1] += bsum[blockIdx.x];
    if (i == 0) rowptr[0] = 0;
}

// no atomics: position comes from rowptr + precomputed rank
__global__ void k_fill(const int* __restrict__ src, const int* __restrict__ dst,
                       const int* __restrict__ rowptr, const int* __restrict__ rank,
                       int* __restrict__ col) {
    int e = blockIdx.x * blockDim.x + threadIdx.x;
    if (e < N_EDGES) {
        int d = dst[e];
        col[rowptr[d] + rank[e]] = src[e];
    }
}

// xs = bf16(dis * x)  (layer-1 gather source; 8 elems/thread)
__global__ void k_prepx(const float* __restrict__ x, const float* __restrict__ dis,
                        ushort* __restrict__ xs) {
    int t = blockIdx.x * blockDim.x + threadIdx.x;
    if (t < N_NODES * 8) {
        int n = t >> 3;
        float d = dis[n];
        const float4* px = (const float4*)(x + (size_t)t * 8);
        float4 a = px[0], b = px[1];
        ushort o[8] = { f2bf(d*a.x), f2bf(d*a.y), f2bf(d*a.z), f2bf(d*a.w),
                        f2bf(d*b.x), f2bf(d*b.y), f2bf(d*b.z), f2bf(d*b.w) };
        *(uint4*)(xs + (size_t)t * 8) = *(const uint4*)o;
    }
}

// Wt[w][f][k] = f16(W_w[k][f])  — transposed f16 weights for MFMA B-fragments
__global__ void k_prepw(const float* __restrict__ W1, const float* __restrict__ W2,
                        const float* __restrict__ W3, _Float16* __restrict__ Wt) {
    int t = blockIdx.x * blockDim.x + threadIdx.x;
    if (t < 3 * 4096) {
        int wsel = t >> 12, i = t & 4095;
        int k = i >> 6, f = i & 63;
        const float* Ws = (wsel == 0) ? W1 : (wsel == 1) ? W2 : W3;
        Wt[wsel * 4096 + f * 64 + k] = (_Float16)Ws[k * 64 + f];
    }
}

__device__ inline void drain4(const ushort* __restrict__ hs, const int* __restrict__ col,
                              int lane, int e, int eend, float& acc) {
    for (; e + 3 < eend; e += 4) {
        float v0 = bf2f(hs[(size_t)col[e]   * F + lane]);
        float v1 = bf2f(hs[(size_t)col[e+1] * F + lane]);
        float v2 = bf2f(hs[(size_t)col[e+2] * F + lane]);
        float v3 = bf2f(hs[(size_t)col[e+3] * F + lane]);
        acc += v0 + v1 + v2 + v3;
    }
    for (; e < eend; ++e) acc += bf2f(hs[(size_t)col[e] * F + lane]);
}

// Fused GCN layer (agg-first, barrier-free):
//   g[n] = dis[n]*( hs[n] + sum_{e:dst=n} hs[src] )   (hs pre-scaled by dis; f16 LDS)
//   h'   = relu( g[n]·W + b );  out = bf16( SCALE ? dis*h' : h' )
// Block = 64 nodes, 4 waves; wave owns rows [16w,16w+16).
// Phase1: 4 rounds of 4 nodes jointly, 16 gathers in flight, register acc
// (pure adds, boundaries implicit in loop bounds), 4-deep drains.
// Phase2: MFMA reads ONLY the wave's own LDS strip -> same-wave ordering, no barrier.
// Epilogue: direct global ushort stores (C/D layout col=lane&15,row=(lane>>4)*4+reg)
// -> no LDS round-trip, no barriers anywhere; waves fully independent.
template<bool RELU, bool SCALE>
__global__ __launch_bounds__(256) void k_layer(const ushort* __restrict__ hs,
                                               const int* __restrict__ rowptr,
                                               const int* __restrict__ col,
                                               const float* __restrict__ dis,
                                               const _Float16* __restrict__ Wt,
                                               const float* __restrict__ bias,
                                               ushort* __restrict__ hout) {
    __shared__ _Float16 g[64 * 64];
    int lane = threadIdx.x & 63;
    int w    = __builtin_amdgcn_readfirstlane(threadIdx.x >> 6);
    int chunk = blockIdx.x * 64;
    int wr16 = w * 16;
    int nbase = chunk + wr16;

    // ---------- phase 1: aggregate 16 nodes (4 rounds x 4 nodes) ----------
    for (int p = 0; p < 4; ++p) {
        int na = nbase + 4 * p;
        int rowb = wr16 + 4 * p;
        int i0 = min(na,     N_NODES), i1 = min(na + 1, N_NODES);
        int i2 = min(na + 2, N_NODES), i3 = min(na + 3, N_NODES);
        int i4 = min(na + 4, N_NODES);
        int q0 = rowptr[i0], q1 = rowptr[i1], q2 = rowptr[i2];
        int q3 = rowptr[i3], q4 = rowptr[i4];
        // self-loop init (invalid nodes have empty ranges and acc=0)
        float a0 = (na     < N_NODES) ? bf2f(hs[(size_t)na      * F + lane]) : 0.f;
        float a1 = (na + 1 < N_NODES) ? bf2f(hs[(size_t)(na + 1) * F + lane]) : 0.f;
        float a2 = (na + 2 < N_NODES) ? bf2f(hs[(size_t)(na + 2) * F + lane]) : 0.f;
        float a3 = (na + 3 < N_NODES) ? bf2f(hs[(size_t)(na + 3) * F + lane]) : 0.f;
        int ea = q0, eb = q1, ec = q2, ed = q3;
        // joint phase: 16 independent gathers in flight, accumulate = pure adds
        while (ea + 3 < q1 && eb + 3 < q2 && ec + 3 < q3 && ed + 3 < q4) {
            int sa0 = col[ea], sa1 = col[ea+1], sa2 = col[ea+2], sa3 = col[ea+3];
            int sb0 = col[eb], sb1 = col[eb+1], sb2 = col[eb+2], sb3 = col[eb+3];
            int sc0 = col[ec], sc1 = col[ec+1], sc2 = col[ec+2], sc3 = col[ec+3];
            int sd0 = col[ed], sd1 = col[ed+1], sd2 = col[ed+2], sd3 = col[ed+3];
            float va0 = bf2f(hs[(size_t)sa0 * F + lane]);
            float va1 = bf2f(hs[(size_t)sa1 * F + lane]);
            float va2 = bf2f(hs[(size_t)sa2 * F + lane]);
            float va3 = bf2f(hs[(size_t)sa3 * F + lane]);
            float vb0 = bf2f(hs[(size_t)sb0 * F + lane]);
            float vb1 = bf2f(hs[(size_t)sb1 * F + lane]);
            float vb2 = bf2f(hs[(size_t)sb2 * F + lane]);
            float vb3 = bf2f(hs[(size_t)sb3 * F + lane]);
            float vc0 = bf2f(hs[(size_t)sc0 * F + lane]);
            float vc1 = bf2f(hs[(size_t)sc1 * F + lane]);
            float vc2 = bf2f(hs[(size_t)sc2 * F + lane]);
            float vc3 = bf2f(hs[(size_t)sc3 * F + lane]);
            float vd0 = bf2f(hs[(size_t)sd0 * F + lane]);
            float vd1 = bf2f(hs[(size_t)sd1 * F + lane]);
            float vd2 = bf2f(hs[(size_t)sd2 * F + lane]);
            float vd3 = bf2f(hs[(size_t)sd3 * F + lane]);
            a0 += va0 + va1 + va2 + va3;
            a1 += vb0 + vb1 + vb2 + vb3;
            a2 += vc0 + vc1 + vc2 + vc3;
            a3 += vd0 + vd1 + vd2 + vd3;
            ea += 4; eb += 4; ec += 4; ed += 4;
        }
        drain4(hs, col, lane, ea, q1, a0);
        drain4(hs, col, lane, eb, q2, a1);
        drain4(hs, col, lane, ec, q3, a2);
        drain4(hs, col, lane, ed, q4, a3);
        // fold dis and store f16 rows (own strip only)
        float d0 = (na     < N_NODES) ? dis[na]     : 0.f;
        float d1 = (na + 1 < N_NODES) ? dis[na + 1] : 0.f;
        float d2 = (na + 2 < N_NODES) ? dis[na + 2] : 0.f;
        float d3 = (na + 3 < N_NODES) ? dis[na + 3] : 0.f;
        g[(rowb    ) * 64 + lane] = (_Float16)(d0 * a0);
        g[(rowb + 1) * 64 + lane] = (_Float16)(d1 * a1);
        g[(rowb + 2) * 64 + lane] = (_Float16)(d2 * a2);
        g[(rowb + 3) * 64 + lane] = (_Float16)(d3 * a3);
    }
    // no barrier: phase 2 reads only this wave's own strip (same-wave LDS ordering)

    // ---------- phase 2: C[16x64] = g_strip · W via MFMA ----------
    int l15 = lane & 15, lh = lane >> 4;
    half8 bfrag[2][4];
#pragma unroll
    for (int ks = 0; ks < 2; ++ks)
#pragma unroll
        for (int nt = 0; nt < 4; ++nt)
            bfrag[ks][nt] = *(const half8*)(Wt + (nt * 16 + l15) * 64 + ks * 32 + lh * 8);

    f32x4 acc4[4] = {};
#pragma unroll
    for (int ks = 0; ks < 2; ++ks) {
        half8 a = *(const half8*)(&g[(wr16 + l15) * 64 + ks * 32 + lh * 8]);
#pragma unroll
        for (int nt = 0; nt < 4; ++nt)
            acc4[nt] = __builtin_amdgcn_mfma_f32_16x16x32_f16(a, bfrag[ks][nt], acc4[nt], 0, 0, 0);
    }

    // ---------- epilogue: direct global stores (no LDS, no barrier) ----------
    float bvals[4];
#pragma unroll
    for (int nt = 0; nt < 4; ++nt) bvals[nt] = bias[nt * 16 + l15];
#pragma unroll
    for (int rr = 0; rr < 4; ++rr) {
        int row = wr16 + lh * 4 + rr;
        int ng = chunk + row;
        if (ng < N_NODES) {
            float ds2 = 1.f;
            if (SCALE) ds2 = dis[ng];
#pragma unroll
            for (int nt = 0; nt < 4; ++nt) {
                float vv = acc4[nt][rr] + bvals[nt];
                if (RELU) vv = fmaxf(vv, 0.f);
                if (SCALE) vv *= ds2;
                hout[(size_t)ng * F + nt * 16 + l15] = f2bf(vv);
            }
        }
    }
}

__global__ void k_pool_init(float* __restrict__ out) {
    int i = blockIdx.x * blockDim.x + threadIdx.x;
    if (i < N_GRAPHS * F) out[i] = -INFINITY;
}

__device__ inline void atomicMaxFloat(float* addr, float v) {
    if (v >= 0.f) atomicMax((int*)addr, __float_as_int(v));
    else          atomicMin((unsigned int*)addr, __float_as_uint(v));
}

// batch is sorted: each wave scans a contiguous chunk, flushes on boundary.
__global__ __launch_bounds__(256) void k_pool(const ushort* __restrict__ h,
                                              const int* __restrict__ batch,
                                              float* __restrict__ out) {
    int lane = threadIdx.x & 63;
    int wid  = __builtin_amdgcn_readfirstlane((blockIdx.x * blockDim.x + threadIdx.x) >> 6);
    int nwaves = (gridDim.x * blockDim.x) >> 6;
    int per = (N_NODES + nwaves - 1) / nwaves;
    int n0 = wid * per, n1 = min(N_NODES, n0 + per);
    if (n0 >= n1) return;
    float acc = -INFINITY;
    int cur = batch[n0];
    for (int n = n0; n < n1; ++n) {
        int g = batch[n];
        if (g != cur) {
            atomicMaxFloat(&out[cur * F + lane], acc);
            acc = -INFINITY; cur = g;
        }
        acc = fmaxf(acc, bf2f(h[(size_t)n * F + lane]));
    }
    atomicMaxFloat(&out[cur * F + lane], acc);
}

extern "C" void kernel_launch(void* const* d_in, const int* in_sizes, int n_in,
                              void* d_out, int out_size, void* d_ws, size_t ws_size,
                              hipStream_t stream) {
    const float* x     = (const float*)d_in[0];
    const int*   ei    = (const int*)d_in[1];
    const int*   batch = (const int*)d_in[2];
    const float* W1 = (const float*)d_in[3];
    const float* b1 = (const float*)d_in[4];
    const float* W2 = (const float*)d_in[5];
    const float* b2 = (const float*)d_in[6];
    const float* W3 = (const float*)d_in[7];
    const float* b3 = (const float*)d_in[8];
    const int* src = ei;
    const int* dst = ei + N_EDGES;

    char* ws = (char*)d_ws;
    ushort*   bufA   = (ushort*)(ws + OFF_BUFA);
    int*      rank   = (int*)(ws + OFF_BUFA);     // alias: live only during CSR build
    ushort*   bufB   = (ushort*)(ws + OFF_BUFB);
    float*    dis    = (float*)(ws + OFF_DIS);
    int*      degcnt = (int*)(ws + OFF_DEG);
    int*      rowptr = (int*)(ws + OFF_ROWP);
    int*      col    = (int*)(ws + OFF_COL);
    int*      bsum   = (int*)(ws + OFF_BSUM);
    _Float16* wt     = (_Float16*)(ws + OFF_WT);
    float*    out    = (float*)d_out;

    // CSR build
    k_zero<<<(N_NODES + 255) / 256, 256, 0, stream>>>(degcnt, N_NODES);
    k_degree<<<(N_EDGES + 255) / 256, 256, 0, stream>>>(dst, degcnt, rank);
    k_scan1<<<98, 1024, 0, stream>>>(degcnt, rowptr, bsum, dis);
    k_scan2<<<1, 128, 0, stream>>>(bsum, 98);
    k_scan3<<<98, 1024, 0, stream>>>(rowptr, bsum);
    k_fill<<<(N_EDGES + 255) / 256, 256, 0, stream>>>(src, dst, rowptr, rank, col);

    // prep: xs = bf16(dis*x) (overwrites rank region), Wt = f16 transposed weights
    k_prepx<<<(N_NODES * 8 + 255) / 256, 256, 0, stream>>>(x, dis, bufA);
    k_prepw<<<48, 256, 0, stream>>>(W1, W2, W3, wt);

    const int LBLOCKS = (N_NODES + 63) / 64;   // 1563
    k_layer<true,  true ><<<LBLOCKS, 256, 0, stream>>>(bufA, rowptr, col, dis, wt,        b1, bufB);
    k_layer<true,  true ><<<LBLOCKS, 256, 0, stream>>>(bufB, rowptr, col, dis, wt + 4096, b2, bufA);
    k_layer<false, false><<<LBLOCKS, 256, 0, stream>>>(bufA, rowptr, col, dis, wt + 8192, b3, bufB);

    // global max pool
    k_pool_init<<<(N_GRAPHS * F + 255) / 256, 256, 0, stream>>>(out);
    k_pool<<<512, 256, 0, stream>>>(bufB, batch, out);
}